// Round 8
// baseline (2755.950 us; speedup 1.0000x reference)
//
#include <hip/hip_runtime.h>

#define BATCH 16
#define NROW  256
#define MCOL  256
#define CDIM  4096
#define INF_F 1e30f
#define CROWS 150      // rows of C cached in LDS (150*256*4 = 153600 B)
#define NSCALE 4
#define SWEEPCAP 40
#define TOTBUDGET 120

// ---------------------------------------------------------------------------
// Fused cost kernel: per-(b,n) softmax stats over C=4096, then 256 cost cols.
// ---------------------------------------------------------------------------
__global__ __launch_bounds__(256)
void cost_fused_kernel(const float* __restrict__ pred_ctrl,
                       const float* __restrict__ logits,
                       const float* __restrict__ gt_ctrl,
                       const int* __restrict__ gt_labels,
                       float* __restrict__ Cout) {
    const int bn = blockIdx.x;
    const int b  = bn >> 8;
    const int t  = threadIdx.x;
    const int lane = t & 63, wave = t >> 6;
    const float* rp = logits + (size_t)bn * CDIM;

    __shared__ float part[4];
    __shared__ float smax, ssum;

    float mx = -INF_F;
    for (int c = t; c < CDIM; c += 256) mx = fmaxf(mx, rp[c]);
    for (int off = 32; off; off >>= 1) mx = fmaxf(mx, __shfl_down(mx, off));
    if (lane == 0) part[wave] = mx;
    __syncthreads();
    if (t == 0) smax = fmaxf(fmaxf(part[0], part[1]), fmaxf(part[2], part[3]));
    __syncthreads();
    mx = smax;

    float s = 0.f;
    for (int c = t; c < CDIM; c += 256) s += expf(rp[c] - mx);
    for (int off = 32; off; off >>= 1) s += __shfl_down(s, off);
    __syncthreads();
    if (lane == 0) part[wave] = s;
    __syncthreads();
    if (t == 0) ssum = part[0] + part[1] + part[2] + part[3];
    __syncthreads();

    const float rmax = smax, rsum = ssum;
    const int m = t;

    const float* pp = pred_ctrl + (size_t)bn * 8;
    const float p0 = pp[0], p1 = pp[1], p2 = pp[2], p3 = pp[3];
    const float p4 = pp[4], p5 = pp[5], p6 = pp[6], p7 = pp[7];

    const float* gp = gt_ctrl + ((size_t)b * MCOL + m) * 8;
    const float4 ga = *(const float4*)gp;
    const float4 gb = *(const float4*)(gp + 4);

    const int lbl = gt_labels[b * MCOL + m];
    const float prob = expf(rp[lbl] - rmax) / rsum;

    float cb = fabsf(p0 - ga.x);
    cb += fabsf(p1 - ga.y);
    cb += fabsf(p2 - ga.z);
    cb += fabsf(p3 - ga.w);
    cb += fabsf(p4 - gb.x);
    cb += fabsf(p5 - gb.y);
    cb += fabsf(p6 - gb.z);
    cb += fabsf(p7 - gb.w);

    Cout[(size_t)bn * MCOL + m] = -prob + 5.0f * cb;
}

// ---------------------------------------------------------------------------
// Helpers
// ---------------------------------------------------------------------------
__device__ __forceinline__ unsigned ordkey(float f) {
    unsigned b = __float_as_uint(f);
    return (b & 0x80000000u) ? ~b : (b | 0x80000000u);
}
__device__ __forceinline__ float unordkey(unsigned k) {
    unsigned b = (k & 0x80000000u) ? (k ^ 0x80000000u) : ~k;
    return __uint_as_float(b);
}

template<int CTRL>
__device__ __forceinline__ unsigned dpp_min_step(unsigned x) {
    const unsigned o = (unsigned)__builtin_amdgcn_update_dpp((int)x, (int)x, CTRL, 0xf, 0xf, false);
    return o < x ? o : x;
}
__device__ __forceinline__ unsigned wave_min_u32(unsigned x) {
    x = dpp_min_step<0x111>(x);   // row_shr:1
    x = dpp_min_step<0x112>(x);   // row_shr:2
    x = dpp_min_step<0x114>(x);   // row_shr:4
    x = dpp_min_step<0x118>(x);   // row_shr:8
    x = dpp_min_step<0x142>(x);   // row_bcast:15
    x = dpp_min_step<0x143>(x);   // row_bcast:31
    return (unsigned)__builtin_amdgcn_readlane((int)x, 63);
}

__device__ __forceinline__ float readlane_f(float x, int lane_idx) {
    return __int_as_float(__builtin_amdgcn_readlane(__float_as_int(x), lane_idx));
}
__device__ __forceinline__ float sel4f(float a0, float a1, float a2, float a3, int s) {
    float r = a0;
    r = (s == 1) ? a1 : r;
    r = (s == 2) ? a2 : r;
    r = (s == 3) ? a3 : r;
    return r;
}
__device__ __forceinline__ int sel4i(int a0, int a1, int a2, int a3, int s) {
    int r = a0;
    r = (s == 1) ? a1 : r;
    r = (s == 2) ? a2 : r;
    r = (s == 3) ? a3 : r;
    return r;
}

// ---------------------------------------------------------------------------
// LSA, one wave per batch. Lane t owns rows AND cols 4t..4t+3.
// Stage 1: v[j] = column min (prices) + LDS row staging.
// Stage 2: eps-scaling Jacobi auction (full rematch per scale, prices
//   persist). Bid = (gap + eps) via LDS u64 atomicMax; winner takes column,
//   price drops by bid. v only decreases -> reduced costs only rise.
// Repair: u_i = exact row-min of (c - v) (dual feasible by construction);
//   keep matches only if exactly tight -> complementary slackness holds.
// Stage 3: single-source SAP per remaining free row (exact JV phase) ->
//   unique optimum == reference, regardless of auction quality.
// ---------------------------------------------------------------------------
__global__ __launch_bounds__(64)
void lsa_kernel(const float* __restrict__ Cmat,
                float* __restrict__ out_row,
                float* __restrict__ out_col) {
    const int b = blockIdx.x;
    const int t = threadIdx.x;
    const int jb = 4 * t;
    const float* C = Cmat + (size_t)b * NROW * MCOL;

    __shared__ float Cc[CROWS][MCOL];               // 153600 B row cache
    __shared__ __align__(16) float v_lds[MCOL];     // col prices (authoritative)
    __shared__ unsigned long long bid_s[MCOL];      // bid keys
    __shared__ int r4c_s[MCOL];
    __shared__ int c4r_s[NROW];

    // ---------------- stage 1: column minima + LDS staging ----------------
    float m0 = INF_F, m1 = INF_F, m2 = INF_F, m3 = INF_F;
    for (int i = 0; i < NROW; i++) {
        const float4 c4 = *(const float4*)(C + (size_t)i * MCOL + jb);
        if (i < CROWS) *(float4*)&Cc[i][jb] = c4;
        m0 = fminf(m0, c4.x); m1 = fminf(m1, c4.y);
        m2 = fminf(m2, c4.z); m3 = fminf(m3, c4.w);
    }
    float u0 = 0.f, u1 = 0.f, u2 = 0.f, u3 = 0.f;   // u[i] set at repair

    v_lds[jb + 0] = m0; v_lds[jb + 1] = m1;
    v_lds[jb + 2] = m2; v_lds[jb + 3] = m3;
    __syncthreads();

    // ---------------- stage 2: eps-scaling Jacobi auction ----------------
    const float eps_sched[NSCALE] = {1.0f, 0.1f, 0.01f, 0.001f};
    int budget = TOTBUDGET;
    for (int scale = 0; scale < NSCALE; scale++) {
        const float eps = eps_sched[scale];
        *(int4*)&c4r_s[jb] = make_int4(-1, -1, -1, -1);   // full rematch
        *(int4*)&r4c_s[jb] = make_int4(-1, -1, -1, -1);
        __syncthreads();

        for (int sweep = 0; sweep < SWEEPCAP && budget > 0; sweep++, budget--) {
            const int4 myc = *(const int4*)&c4r_s[jb];
            const unsigned long long f0 = __ballot(myc.x < 0);
            const unsigned long long f1 = __ballot(myc.y < 0);
            const unsigned long long f2 = __ballot(myc.z < 0);
            const unsigned long long f3 = __ballot(myc.w < 0);
            if (!(f0 | f1 | f2 | f3)) break;

            bid_s[jb + 0] = 0; bid_s[jb + 1] = 0;
            bid_s[jb + 2] = 0; bid_s[jb + 3] = 0;
            __syncthreads();

            const bool fr[4] = { myc.x < 0, myc.y < 0, myc.z < 0, myc.w < 0 };
            int bj[4]; float bump[4]; unsigned long long key[4];

            #pragma unroll
            for (int s = 0; s < 4; s++) {
                bj[s] = -1; bump[s] = 0.f; key[s] = 0;
                if (!fr[s]) continue;
                const int i = jb + s;
                const float* rowp = C + (size_t)i * MCOL;   // GLOBAL: no LDS conflicts
                float b1 = INF_F, b2 = INF_F; int idx = 0;
                for (int j = 0; j < MCOL; j += 4) {
                    const float4 vv = *(const float4*)&v_lds[j];   // broadcast
                    const float4 cc = *(const float4*)(rowp + j);
                    float d;
                    d = cc.x - vv.x; b2 = fminf(b2, fmaxf(b1, d)); idx = d < b1 ? j + 0 : idx; b1 = fminf(b1, d);
                    d = cc.y - vv.y; b2 = fminf(b2, fmaxf(b1, d)); idx = d < b1 ? j + 1 : idx; b1 = fminf(b1, d);
                    d = cc.z - vv.z; b2 = fminf(b2, fmaxf(b1, d)); idx = d < b1 ? j + 2 : idx; b1 = fminf(b1, d);
                    d = cc.w - vv.w; b2 = fminf(b2, fmaxf(b1, d)); idx = d < b1 ? j + 3 : idx; b1 = fminf(b1, d);
                }
                bump[s] = (b2 - b1) + eps;
                bj[s] = idx;
                key[s] = ((unsigned long long)ordkey(bump[s]) << 32) | (unsigned)i;
                atomicMax(&bid_s[idx], key[s]);
            }
            __syncthreads();

            int kold[4];
            #pragma unroll
            for (int s = 0; s < 4; s++) {
                kold[s] = -2;   // -2 = not a winner
                if (bj[s] >= 0 && bid_s[bj[s]] == key[s]) kold[s] = r4c_s[bj[s]];
            }
            __syncthreads();

            #pragma unroll
            for (int s = 0; s < 4; s++) {
                if (kold[s] >= -1) {
                    const int i = jb + s, j1 = bj[s];
                    r4c_s[j1] = i;
                    c4r_s[i] = j1;
                    if (kold[s] >= 0) c4r_s[kold[s]] = -1;
                    v_lds[j1] -= bump[s];
                }
            }
            __syncthreads();
        }
    }

    // ---------------- repair: exact duals + tightness filter ----------------
    {
        float uu[4];
        #pragma unroll
        for (int s = 0; s < 4; s++) {
            const int i = jb + s;
            const float* rowp = C + (size_t)i * MCOL;
            float b1 = INF_F;
            for (int j = 0; j < MCOL; j += 4) {
                const float4 vv = *(const float4*)&v_lds[j];
                const float4 cc = *(const float4*)(rowp + j);
                b1 = fminf(b1, cc.x - vv.x);
                b1 = fminf(b1, cc.y - vv.y);
                b1 = fminf(b1, cc.z - vv.z);
                b1 = fminf(b1, cc.w - vv.w);
            }
            uu[s] = b1;
            const int jm = c4r_s[i];
            if (jm >= 0) {
                const float rm = rowp[jm] - v_lds[jm];
                if (rm > b1) { c4r_s[i] = -1; r4c_s[jm] = -1; }  // not tight
            }
        }
        u0 = uu[0]; u1 = uu[1]; u2 = uu[2]; u3 = uu[3];
    }
    __syncthreads();

    // register mirrors
    int4 q;
    q = *(const int4*)&r4c_s[jb];
    int rc0 = q.x, rc1 = q.y, rc2 = q.z, rc3 = q.w;
    q = *(const int4*)&c4r_s[jb];
    int cr0 = q.x, cr1 = q.y, cr2 = q.z, cr3 = q.w;
    const float4 vq = *(const float4*)&v_lds[jb];
    float v0 = vq.x, v1 = vq.y, v2 = vq.z, v3 = vq.w;

    // ---------------- stage 3: single-source SAP per free row (exact) --------
    unsigned long long mm0 = __ballot(cr0 < 0);
    unsigned long long mm1 = __ballot(cr1 < 0);
    unsigned long long mm2 = __ballot(cr2 < 0);
    unsigned long long mm3 = __ballot(cr3 < 0);

    while (mm0 | mm1 | mm2 | mm3) {
        int cur;
        if      (mm0) { const int l = __ffsll(mm0) - 1; mm0 &= mm0 - 1; cur = 4 * l + 0; }
        else if (mm1) { const int l = __ffsll(mm1) - 1; mm1 &= mm1 - 1; cur = 4 * l + 1; }
        else if (mm2) { const int l = __ffsll(mm2) - 1; mm2 &= mm2 - 1; cur = 4 * l + 2; }
        else          { const int l = __ffsll(mm3) - 1; mm3 &= mm3 - 1; cur = 4 * l + 3; }

        float s0 = INF_F, s1 = INF_F, s2 = INF_F, s3 = INF_F;  // spc
        int   p0 = -1,    p1 = -1,    p2 = -1,    p3 = -1;     // path
        float e0 = 0.f, e1 = 0.f, e2 = 0.f, e3 = 0.f;          // entering dist
        int scmask = 0, srmask = 0;
        int i = cur, sink = -1;
        float minVal = 0.f;

        for (int it = 0; it < MCOL; it++) {
            if ((i >> 2) == t) {            // mark scanned + record entering dist
                const int s = i & 3;
                srmask |= 1 << s;
                e0 = s == 0 ? minVal : e0; e1 = s == 1 ? minVal : e1;
                e2 = s == 2 ? minVal : e2; e3 = s == 3 ? minVal : e3;
            }
            const float ui = readlane_f(sel4f(u0, u1, u2, u3, i & 3), i >> 2);
            float4 c4;
            if (i < CROWS) c4 = *(const float4*)&Cc[i][jb];
            else           c4 = *(const float4*)(C + (size_t)i * MCOL + jb);
            const float base = minVal - ui;
            float d;
            d = base + c4.x - v0; if (!(scmask & 1) && d < s0) { s0 = d; p0 = i; }
            d = base + c4.y - v1; if (!(scmask & 2) && d < s1) { s1 = d; p1 = i; }
            d = base + c4.z - v2; if (!(scmask & 4) && d < s2) { s2 = d; p2 = i; }
            d = base + c4.w - v3; if (!(scmask & 8) && d < s3) { s3 = d; p3 = i; }

            unsigned lmin = 0xFFFFFFFFu; int lslot = 0, lrc = -1;
            if (!(scmask & 1)) { const unsigned k = ordkey(s0); if (k < lmin) { lmin = k; lslot = 0; lrc = rc0; } }
            if (!(scmask & 2)) { const unsigned k = ordkey(s1); if (k < lmin) { lmin = k; lslot = 1; lrc = rc1; } }
            if (!(scmask & 4)) { const unsigned k = ordkey(s2); if (k < lmin) { lmin = k; lslot = 2; lrc = rc2; } }
            if (!(scmask & 8)) { const unsigned k = ordkey(s3); if (k < lmin) { lmin = k; lslot = 3; lrc = rc3; } }

            const unsigned g = wave_min_u32(lmin);
            const unsigned long long bal = __ballot(lmin == g);
            const int w = __ffsll(bal) - 1;
            const int pk = __builtin_amdgcn_readlane(((lrc + 1) << 2) | lslot, w);
            const int mj = 4 * w + (pk & 3);
            const int rcx = (pk >> 2) - 1;
            minVal = unordkey(g);

            if (w == t) scmask |= 1 << (pk & 3);
            if (rcx < 0) { sink = mj; break; }
            i = rcx;
        }

        // dual updates (reference formulas; e_cur = 0 so cur gets +minVal)
        if (srmask & 1) u0 += minVal - e0;
        if (srmask & 2) u1 += minVal - e1;
        if (srmask & 4) u2 += minVal - e2;
        if (srmask & 8) u3 += minVal - e3;
        if (scmask & 1) v0 -= (minVal - s0);
        if (scmask & 2) v1 -= (minVal - s1);
        if (scmask & 4) v2 -= (minVal - s2);
        if (scmask & 8) v3 -= (minVal - s3);

        // augment along predecessor path (registers + readlane)
        int j = sink;
        for (int g2 = 0; g2 < NROW; g2++) {
            const int pi = __builtin_amdgcn_readlane(
                sel4i(p0, p1, p2, p3, j & 3), j >> 2);        // path[j]
            if ((j >> 2) == t) {                              // row4col[j] = pi
                const int s = j & 3;
                rc0 = s == 0 ? pi : rc0; rc1 = s == 1 ? pi : rc1;
                rc2 = s == 2 ? pi : rc2; rc3 = s == 3 ? pi : rc3;
            }
            const int jn = __builtin_amdgcn_readlane(
                sel4i(cr0, cr1, cr2, cr3, pi & 3), pi >> 2);  // old col4row[pi]
            if ((pi >> 2) == t) {                             // col4row[pi] = j
                const int s = pi & 3;
                cr0 = s == 0 ? j : cr0; cr1 = s == 1 ? j : cr1;
                cr2 = s == 2 ? j : cr2; cr3 = s == 3 ? j : cr3;
            }
            if (jn < 0) break;                                // reached free row (cur)
            j = jn;
        }
    }

    out_row[b * NROW + jb + 0] = (float)(jb + 0);
    out_row[b * NROW + jb + 1] = (float)(jb + 1);
    out_row[b * NROW + jb + 2] = (float)(jb + 2);
    out_row[b * NROW + jb + 3] = (float)(jb + 3);
    out_col[b * NROW + jb + 0] = (float)cr0;
    out_col[b * NROW + jb + 1] = (float)cr1;
    out_col[b * NROW + jb + 2] = (float)cr2;
    out_col[b * NROW + jb + 3] = (float)cr3;
}

// ---------------------------------------------------------------------------
extern "C" void kernel_launch(void* const* d_in, const int* in_sizes, int n_in,
                              void* d_out, int out_size, void* d_ws, size_t ws_size,
                              hipStream_t stream) {
    const float* pred_ctrl   = (const float*)d_in[0];
    const float* pred_logits = (const float*)d_in[1];
    const float* gt_ctrl     = (const float*)d_in[2];
    const int*   gt_labels   = (const int*)d_in[3];

    float* out     = (float*)d_out;
    float* out_row = out;
    float* out_col = out + BATCH * NROW;
    float* Cout    = out + 2 * BATCH * NROW;

    cost_fused_kernel<<<BATCH * NROW, 256, 0, stream>>>(pred_ctrl, pred_logits,
                                                        gt_ctrl, gt_labels, Cout);
    lsa_kernel<<<BATCH, 64, 0, stream>>>(Cout, out_row, out_col);
}

// Round 9
// 2536.523 us; speedup vs baseline: 1.0865x; 1.0865x over previous
//
#include <hip/hip_runtime.h>

#define BATCH 16
#define NROW  256
#define MCOL  256
#define CDIM  4096
#define INF_F 1e30f
#define CROWS 150      // rows of C cached in LDS (150*256*4 = 153600 B)
#define NSCALE 3
#define TOTBUDGET 120

// ---------------------------------------------------------------------------
// Fused cost kernel: per-(b,n) softmax stats over C=4096, then 256 cost cols.
// ---------------------------------------------------------------------------
__global__ __launch_bounds__(256)
void cost_fused_kernel(const float* __restrict__ pred_ctrl,
                       const float* __restrict__ logits,
                       const float* __restrict__ gt_ctrl,
                       const int* __restrict__ gt_labels,
                       float* __restrict__ Cout) {
    const int bn = blockIdx.x;
    const int b  = bn >> 8;
    const int t  = threadIdx.x;
    const int lane = t & 63, wave = t >> 6;
    const float* rp = logits + (size_t)bn * CDIM;

    __shared__ float part[4];
    __shared__ float smax, ssum;

    float mx = -INF_F;
    for (int c = t; c < CDIM; c += 256) mx = fmaxf(mx, rp[c]);
    for (int off = 32; off; off >>= 1) mx = fmaxf(mx, __shfl_down(mx, off));
    if (lane == 0) part[wave] = mx;
    __syncthreads();
    if (t == 0) smax = fmaxf(fmaxf(part[0], part[1]), fmaxf(part[2], part[3]));
    __syncthreads();
    mx = smax;

    float s = 0.f;
    for (int c = t; c < CDIM; c += 256) s += expf(rp[c] - mx);
    for (int off = 32; off; off >>= 1) s += __shfl_down(s, off);
    __syncthreads();
    if (lane == 0) part[wave] = s;
    __syncthreads();
    if (t == 0) ssum = part[0] + part[1] + part[2] + part[3];
    __syncthreads();

    const float rmax = smax, rsum = ssum;
    const int m = t;

    const float* pp = pred_ctrl + (size_t)bn * 8;
    const float p0 = pp[0], p1 = pp[1], p2 = pp[2], p3 = pp[3];
    const float p4 = pp[4], p5 = pp[5], p6 = pp[6], p7 = pp[7];

    const float* gp = gt_ctrl + ((size_t)b * MCOL + m) * 8;
    const float4 ga = *(const float4*)gp;
    const float4 gb = *(const float4*)(gp + 4);

    const int lbl = gt_labels[b * MCOL + m];
    const float prob = expf(rp[lbl] - rmax) / rsum;

    float cb = fabsf(p0 - ga.x);
    cb += fabsf(p1 - ga.y);
    cb += fabsf(p2 - ga.z);
    cb += fabsf(p3 - ga.w);
    cb += fabsf(p4 - gb.x);
    cb += fabsf(p5 - gb.y);
    cb += fabsf(p6 - gb.z);
    cb += fabsf(p7 - gb.w);

    Cout[(size_t)bn * MCOL + m] = -prob + 5.0f * cb;
}

// ---------------------------------------------------------------------------
// Helpers
// ---------------------------------------------------------------------------
__device__ __forceinline__ unsigned ordkey(float f) {
    unsigned b = __float_as_uint(f);
    return (b & 0x80000000u) ? ~b : (b | 0x80000000u);
}
__device__ __forceinline__ float unordkey(unsigned k) {
    unsigned b = (k & 0x80000000u) ? (k ^ 0x80000000u) : ~k;
    return __uint_as_float(b);
}

template<int CTRL>
__device__ __forceinline__ unsigned dpp_min_step(unsigned x) {
    const unsigned o = (unsigned)__builtin_amdgcn_update_dpp((int)x, (int)x, CTRL, 0xf, 0xf, false);
    return o < x ? o : x;
}
__device__ __forceinline__ unsigned wave_min_u32(unsigned x) {
    x = dpp_min_step<0x111>(x);   // row_shr:1
    x = dpp_min_step<0x112>(x);   // row_shr:2
    x = dpp_min_step<0x114>(x);   // row_shr:4
    x = dpp_min_step<0x118>(x);   // row_shr:8
    x = dpp_min_step<0x142>(x);   // row_bcast:15
    x = dpp_min_step<0x143>(x);   // row_bcast:31
    return (unsigned)__builtin_amdgcn_readlane((int)x, 63);
}

__device__ __forceinline__ float readlane_f(float x, int lane_idx) {
    return __int_as_float(__builtin_amdgcn_readlane(__float_as_int(x), lane_idx));
}
__device__ __forceinline__ float sel4f(float a0, float a1, float a2, float a3, int s) {
    float r = a0;
    r = (s == 1) ? a1 : r;
    r = (s == 2) ? a2 : r;
    r = (s == 3) ? a3 : r;
    return r;
}
__device__ __forceinline__ int sel4i(int a0, int a1, int a2, int a3, int s) {
    int r = a0;
    r = (s == 1) ? a1 : r;
    r = (s == 2) ? a2 : r;
    r = (s == 3) ? a3 : r;
    return r;
}

// ---------------------------------------------------------------------------
// LSA, one wave per batch. Lane t owns rows AND cols 4t..4t+3.
// Stage 1: v[j] = column min + argmin row; greedy tight seed; LDS staging.
// Stage 2: eps-scaling Jacobi auction (0.5 / 0.05 / 0.005). Bid = gap + eps
//   via LDS u64 atomicMax; winner takes column, price drops by bid. Prices
//   persist across scales; matching rebuilt (seed kept at scale 0: exactly
//   tight edges satisfy eps-CS for any eps).
// Repair: raise each matched column's price by its slack -> edge becomes
//   tight; recompute exact u_i = rowmin(c - v); drop non-min-attaining
//   matches. Result: feasible duals + CS-tight matching, most matches kept.
// Stage 3: single-source SAP per remaining free row (exact JV phase) ->
//   unique optimum == reference, regardless of auction quality.
// ---------------------------------------------------------------------------
__global__ __launch_bounds__(64)
void lsa_kernel(const float* __restrict__ Cmat,
                float* __restrict__ out_row,
                float* __restrict__ out_col) {
    const int b = blockIdx.x;
    const int t = threadIdx.x;
    const int jb = 4 * t;
    const float* C = Cmat + (size_t)b * NROW * MCOL;

    __shared__ float Cc[CROWS][MCOL];               // 153600 B row cache
    __shared__ __align__(16) float v_lds[MCOL];     // col prices (authoritative)
    __shared__ unsigned long long bid_s[MCOL];      // bid keys; aliased argrow
    __shared__ int r4c_s[MCOL];
    __shared__ int c4r_s[NROW];
    int* const argrow_s = (int*)bid_s;

    // ---------------- stage 1: column minima + argmin + LDS staging ----------
    float m0 = INF_F, m1 = INF_F, m2 = INF_F, m3 = INF_F;
    int   r0 = 0, r1 = 0, r2 = 0, r3 = 0;
    for (int i = 0; i < NROW; i++) {
        const float4 c4 = *(const float4*)(C + (size_t)i * MCOL + jb);
        if (i < CROWS) *(float4*)&Cc[i][jb] = c4;
        if (c4.x < m0) { m0 = c4.x; r0 = i; }
        if (c4.y < m1) { m1 = c4.y; r1 = i; }
        if (c4.z < m2) { m2 = c4.z; r2 = i; }
        if (c4.w < m3) { m3 = c4.w; r3 = i; }
    }
    float u0 = 0.f, u1 = 0.f, u2 = 0.f, u3 = 0.f;   // set at repair

    v_lds[jb + 0] = m0; v_lds[jb + 1] = m1;
    v_lds[jb + 2] = m2; v_lds[jb + 3] = m3;
    argrow_s[jb + 0] = r0; argrow_s[jb + 1] = r1;
    argrow_s[jb + 2] = r2; argrow_s[jb + 3] = r3;
    for (int k = 0; k < 4; k++) { c4r_s[jb + k] = -1; r4c_s[jb + k] = -1; }
    __syncthreads();

    if (t == 0) {   // greedy tight seed on column minima (slack 0 <= any eps)
        for (int j = 0; j < MCOL; j++) {
            const int r = argrow_s[j];
            if (c4r_s[r] < 0) { c4r_s[r] = j; r4c_s[j] = r; }
        }
    }
    __syncthreads();

    // ---------------- stage 2: eps-scaling Jacobi auction ----------------
    const float eps_sched[NSCALE] = {0.5f, 0.05f, 0.005f};
    const int   cap_sched[NSCALE] = {25, 35, 60};
    int budget = TOTBUDGET;
    for (int scale = 0; scale < NSCALE; scale++) {
        const float eps = eps_sched[scale];
        if (scale > 0) {   // rematch from empty; prices persist
            *(int4*)&c4r_s[jb] = make_int4(-1, -1, -1, -1);
            *(int4*)&r4c_s[jb] = make_int4(-1, -1, -1, -1);
            __syncthreads();
        }

        const int cap = cap_sched[scale];
        for (int sweep = 0; sweep < cap && budget > 0; sweep++, budget--) {
            const int4 myc = *(const int4*)&c4r_s[jb];
            const unsigned long long f0 = __ballot(myc.x < 0);
            const unsigned long long f1 = __ballot(myc.y < 0);
            const unsigned long long f2 = __ballot(myc.z < 0);
            const unsigned long long f3 = __ballot(myc.w < 0);
            if (!(f0 | f1 | f2 | f3)) break;

            bid_s[jb + 0] = 0; bid_s[jb + 1] = 0;
            bid_s[jb + 2] = 0; bid_s[jb + 3] = 0;
            __syncthreads();

            const bool fr[4] = { myc.x < 0, myc.y < 0, myc.z < 0, myc.w < 0 };
            int bj[4]; float bump[4]; unsigned long long key[4];

            #pragma unroll
            for (int s = 0; s < 4; s++) {
                bj[s] = -1; bump[s] = 0.f; key[s] = 0;
                if (!fr[s]) continue;
                const int i = jb + s;
                const float* rowp = C + (size_t)i * MCOL;   // GLOBAL: no LDS conflicts
                float b1 = INF_F, b2 = INF_F; int idx = 0;
                for (int j = 0; j < MCOL; j += 4) {
                    const float4 vv = *(const float4*)&v_lds[j];   // broadcast
                    const float4 cc = *(const float4*)(rowp + j);
                    float d;
                    d = cc.x - vv.x; b2 = fminf(b2, fmaxf(b1, d)); idx = d < b1 ? j + 0 : idx; b1 = fminf(b1, d);
                    d = cc.y - vv.y; b2 = fminf(b2, fmaxf(b1, d)); idx = d < b1 ? j + 1 : idx; b1 = fminf(b1, d);
                    d = cc.z - vv.z; b2 = fminf(b2, fmaxf(b1, d)); idx = d < b1 ? j + 2 : idx; b1 = fminf(b1, d);
                    d = cc.w - vv.w; b2 = fminf(b2, fmaxf(b1, d)); idx = d < b1 ? j + 3 : idx; b1 = fminf(b1, d);
                }
                bump[s] = (b2 - b1) + eps;
                bj[s] = idx;
                key[s] = ((unsigned long long)ordkey(bump[s]) << 32) | (unsigned)i;
                atomicMax(&bid_s[idx], key[s]);
            }
            __syncthreads();

            int kold[4];
            #pragma unroll
            for (int s = 0; s < 4; s++) {
                kold[s] = -2;   // -2 = not a winner
                if (bj[s] >= 0 && bid_s[bj[s]] == key[s]) kold[s] = r4c_s[bj[s]];
            }
            __syncthreads();

            #pragma unroll
            for (int s = 0; s < 4; s++) {
                if (kold[s] >= -1) {
                    const int i = jb + s, j1 = bj[s];
                    r4c_s[j1] = i;
                    c4r_s[i] = j1;
                    if (kold[s] >= 0) c4r_s[kold[s]] = -1;
                    v_lds[j1] -= bump[s];
                }
            }
            __syncthreads();
        }
    }

    // ---------------- repair: tighten prices, exact duals, filter ----------
    {
        // scan A: exact row minima under current prices
        float rmold[4];
        #pragma unroll
        for (int s = 0; s < 4; s++) {
            const int i = jb + s;
            const float* rowp = C + (size_t)i * MCOL;
            float b1 = INF_F;
            for (int j = 0; j < MCOL; j += 4) {
                const float4 vv = *(const float4*)&v_lds[j];
                const float4 cc = *(const float4*)(rowp + j);
                b1 = fminf(b1, cc.x - vv.x);
                b1 = fminf(b1, cc.y - vv.y);
                b1 = fminf(b1, cc.z - vv.z);
                b1 = fminf(b1, cc.w - vv.w);
            }
            rmold[s] = b1;
        }
        __syncthreads();
        // raise each matched column's price by its slack (unique col per row)
        #pragma unroll
        for (int s = 0; s < 4; s++) {
            const int i = jb + s;
            const int j1 = c4r_s[i];
            if (j1 >= 0) {
                const float slack = (C[(size_t)i * MCOL + j1] - v_lds[j1]) - rmold[s];
                if (slack > 0.f) v_lds[j1] += slack;
            }
        }
        __syncthreads();
        // scan B: fresh exact duals + tightness filter
        float uu[4];
        #pragma unroll
        for (int s = 0; s < 4; s++) {
            const int i = jb + s;
            const float* rowp = C + (size_t)i * MCOL;
            float b1 = INF_F;
            for (int j = 0; j < MCOL; j += 4) {
                const float4 vv = *(const float4*)&v_lds[j];
                const float4 cc = *(const float4*)(rowp + j);
                b1 = fminf(b1, cc.x - vv.x);
                b1 = fminf(b1, cc.y - vv.y);
                b1 = fminf(b1, cc.z - vv.z);
                b1 = fminf(b1, cc.w - vv.w);
            }
            uu[s] = b1;
            const int j1 = c4r_s[i];
            if (j1 >= 0) {
                const float rm = rowp[j1] - v_lds[j1];
                if (rm > b1) { c4r_s[i] = -1; r4c_s[j1] = -1; }  // not tight
            }
        }
        u0 = uu[0]; u1 = uu[1]; u2 = uu[2]; u3 = uu[3];
    }
    __syncthreads();

    // register mirrors
    int4 q;
    q = *(const int4*)&r4c_s[jb];
    int rc0 = q.x, rc1 = q.y, rc2 = q.z, rc3 = q.w;
    q = *(const int4*)&c4r_s[jb];
    int cr0 = q.x, cr1 = q.y, cr2 = q.z, cr3 = q.w;
    const float4 vq = *(const float4*)&v_lds[jb];
    float v0 = vq.x, v1 = vq.y, v2 = vq.z, v3 = vq.w;

    // ---------------- stage 3: single-source SAP per free row (exact) --------
    unsigned long long mm0 = __ballot(cr0 < 0);
    unsigned long long mm1 = __ballot(cr1 < 0);
    unsigned long long mm2 = __ballot(cr2 < 0);
    unsigned long long mm3 = __ballot(cr3 < 0);

    while (mm0 | mm1 | mm2 | mm3) {
        int cur;
        if      (mm0) { const int l = __ffsll(mm0) - 1; mm0 &= mm0 - 1; cur = 4 * l + 0; }
        else if (mm1) { const int l = __ffsll(mm1) - 1; mm1 &= mm1 - 1; cur = 4 * l + 1; }
        else if (mm2) { const int l = __ffsll(mm2) - 1; mm2 &= mm2 - 1; cur = 4 * l + 2; }
        else          { const int l = __ffsll(mm3) - 1; mm3 &= mm3 - 1; cur = 4 * l + 3; }

        float s0 = INF_F, s1 = INF_F, s2 = INF_F, s3 = INF_F;  // spc
        int   p0 = -1,    p1 = -1,    p2 = -1,    p3 = -1;     // path
        float e0 = 0.f, e1 = 0.f, e2 = 0.f, e3 = 0.f;          // entering dist
        int scmask = 0, srmask = 0;
        int i = cur, sink = -1;
        float minVal = 0.f;

        for (int it = 0; it < MCOL; it++) {
            if ((i >> 2) == t) {            // mark scanned + record entering dist
                const int s = i & 3;
                srmask |= 1 << s;
                e0 = s == 0 ? minVal : e0; e1 = s == 1 ? minVal : e1;
                e2 = s == 2 ? minVal : e2; e3 = s == 3 ? minVal : e3;
            }
            const float ui = readlane_f(sel4f(u0, u1, u2, u3, i & 3), i >> 2);
            float4 c4;
            if (i < CROWS) c4 = *(const float4*)&Cc[i][jb];
            else           c4 = *(const float4*)(C + (size_t)i * MCOL + jb);
            const float base = minVal - ui;
            float d;
            d = base + c4.x - v0; if (!(scmask & 1) && d < s0) { s0 = d; p0 = i; }
            d = base + c4.y - v1; if (!(scmask & 2) && d < s1) { s1 = d; p1 = i; }
            d = base + c4.z - v2; if (!(scmask & 4) && d < s2) { s2 = d; p2 = i; }
            d = base + c4.w - v3; if (!(scmask & 8) && d < s3) { s3 = d; p3 = i; }

            unsigned lmin = 0xFFFFFFFFu; int lslot = 0, lrc = -1;
            if (!(scmask & 1)) { const unsigned k = ordkey(s0); if (k < lmin) { lmin = k; lslot = 0; lrc = rc0; } }
            if (!(scmask & 2)) { const unsigned k = ordkey(s1); if (k < lmin) { lmin = k; lslot = 1; lrc = rc1; } }
            if (!(scmask & 4)) { const unsigned k = ordkey(s2); if (k < lmin) { lmin = k; lslot = 2; lrc = rc2; } }
            if (!(scmask & 8)) { const unsigned k = ordkey(s3); if (k < lmin) { lmin = k; lslot = 3; lrc = rc3; } }

            const unsigned g = wave_min_u32(lmin);
            const unsigned long long bal = __ballot(lmin == g);
            const int w = __ffsll(bal) - 1;
            const int pk = __builtin_amdgcn_readlane(((lrc + 1) << 2) | lslot, w);
            const int mj = 4 * w + (pk & 3);
            const int rcx = (pk >> 2) - 1;
            minVal = unordkey(g);

            if (w == t) scmask |= 1 << (pk & 3);
            if (rcx < 0) { sink = mj; break; }
            i = rcx;
        }

        // dual updates (reference formulas; e_cur = 0 so cur gets +minVal)
        if (srmask & 1) u0 += minVal - e0;
        if (srmask & 2) u1 += minVal - e1;
        if (srmask & 4) u2 += minVal - e2;
        if (srmask & 8) u3 += minVal - e3;
        if (scmask & 1) v0 -= (minVal - s0);
        if (scmask & 2) v1 -= (minVal - s1);
        if (scmask & 4) v2 -= (minVal - s2);
        if (scmask & 8) v3 -= (minVal - s3);

        // augment along predecessor path (registers + readlane)
        int j = sink;
        for (int g2 = 0; g2 < NROW; g2++) {
            const int pi = __builtin_amdgcn_readlane(
                sel4i(p0, p1, p2, p3, j & 3), j >> 2);        // path[j]
            if ((j >> 2) == t) {                              // row4col[j] = pi
                const int s = j & 3;
                rc0 = s == 0 ? pi : rc0; rc1 = s == 1 ? pi : rc1;
                rc2 = s == 2 ? pi : rc2; rc3 = s == 3 ? pi : rc3;
            }
            const int jn = __builtin_amdgcn_readlane(
                sel4i(cr0, cr1, cr2, cr3, pi & 3), pi >> 2);  // old col4row[pi]
            if ((pi >> 2) == t) {                             // col4row[pi] = j
                const int s = pi & 3;
                cr0 = s == 0 ? j : cr0; cr1 = s == 1 ? j : cr1;
                cr2 = s == 2 ? j : cr2; cr3 = s == 3 ? j : cr3;
            }
            if (jn < 0) break;                                // reached free row (cur)
            j = jn;
        }
    }

    out_row[b * NROW + jb + 0] = (float)(jb + 0);
    out_row[b * NROW + jb + 1] = (float)(jb + 1);
    out_row[b * NROW + jb + 2] = (float)(jb + 2);
    out_row[b * NROW + jb + 3] = (float)(jb + 3);
    out_col[b * NROW + jb + 0] = (float)cr0;
    out_col[b * NROW + jb + 1] = (float)cr1;
    out_col[b * NROW + jb + 2] = (float)cr2;
    out_col[b * NROW + jb + 3] = (float)cr3;
}

// ---------------------------------------------------------------------------
extern "C" void kernel_launch(void* const* d_in, const int* in_sizes, int n_in,
                              void* d_out, int out_size, void* d_ws, size_t ws_size,
                              hipStream_t stream) {
    const float* pred_ctrl   = (const float*)d_in[0];
    const float* pred_logits = (const float*)d_in[1];
    const float* gt_ctrl     = (const float*)d_in[2];
    const int*   gt_labels   = (const int*)d_in[3];

    float* out     = (float*)d_out;
    float* out_row = out;
    float* out_col = out + BATCH * NROW;
    float* Cout    = out + 2 * BATCH * NROW;

    cost_fused_kernel<<<BATCH * NROW, 256, 0, stream>>>(pred_ctrl, pred_logits,
                                                        gt_ctrl, gt_labels, Cout);
    lsa_kernel<<<BATCH, 64, 0, stream>>>(Cout, out_row, out_col);
}